// Round 3
// baseline (131.334 us; speedup 1.0000x reference)
//
#include <hip/hip_runtime.h>
#include <cstdint>

// EdgeMLP, all-MFMA: layer1 computed operand-swapped (C = hid^T, lane=edge col),
// layer2 (128->2) as 4 more MFMAs via pure register relabeling (no cross-lane moves).
// Depth-2 pipelined gather. W1 register-resident as bf16 fragments.

constexpr int EMB = 64;
constexpr int HID = 128;

typedef short s16x8 __attribute__((ext_vector_type(8)));
typedef float f32x4 __attribute__((ext_vector_type(4)));

__device__ __forceinline__ unsigned short f2bf(float x) {
    unsigned u = __float_as_uint(x);
    u = (u + 0x7fffu + ((u >> 16) & 1u)) >> 16;   // RNE
    return (unsigned short)u;
}

__device__ __forceinline__ s16x8 load8f(const float* __restrict__ p) {
    float4 a = *reinterpret_cast<const float4*>(p);
    float4 b = *reinterpret_cast<const float4*>(p + 4);
    s16x8 f;
    f[0] = (short)f2bf(a.x); f[1] = (short)f2bf(a.y);
    f[2] = (short)f2bf(a.z); f[3] = (short)f2bf(a.w);
    f[4] = (short)f2bf(b.x); f[5] = (short)f2bf(b.y);
    f[6] = (short)f2bf(b.z); f[7] = (short)f2bf(b.w);
    return f;
}

__global__ void conv_h_kernel(const float* __restrict__ h,
                              unsigned short* __restrict__ hb, int n8) {
    const int i = blockIdx.x * blockDim.x + threadIdx.x;
    if (i >= n8) return;
    const float* p = h + (size_t)i * 8;
    float4 a = *reinterpret_cast<const float4*>(p);
    float4 b = *reinterpret_cast<const float4*>(p + 4);
    unsigned short r[8];
    r[0] = f2bf(a.x); r[1] = f2bf(a.y); r[2] = f2bf(a.z); r[3] = f2bf(a.w);
    r[4] = f2bf(b.x); r[5] = f2bf(b.y); r[6] = f2bf(b.z); r[7] = f2bf(b.w);
    *reinterpret_cast<uint4*>(hb + (size_t)i * 8) = *reinterpret_cast<const uint4*>(r);
}

template<bool BF16H>
__global__ __launch_bounds__(256, 2)
void edge_mlp_mfma2(const float* __restrict__ h,
                    const unsigned short* __restrict__ hb,
                    const int* __restrict__ eidx,
                    const float* __restrict__ W1, const float* __restrict__ b1,
                    const float* __restrict__ W2, const float* __restrict__ b2,
                    float* __restrict__ out, int E, int nTiles)
{
    const int t    = threadIdx.x;
    const int wid  = t >> 6;
    const int lane = t & 63;
    const int tc   = lane & 15;   // edge column (B/C) and A row
    const int bq   = lane >> 4;   // k-group

    // W1^T fragments, used as MFMA operand A: A[m=hidden][k]: lane row = mt*16+tc,
    // k = ks*32 + bq*8 + j.  (Same data layout as the validated R2 B-frag.)
    s16x8 w1f[8][4];
    #pragma unroll
    for (int mt = 0; mt < 8; ++mt)
        #pragma unroll
        for (int ks = 0; ks < 4; ++ks) {
            s16x8 f;
            #pragma unroll
            for (int j = 0; j < 8; ++j)
                f[j] = (short)f2bf(W1[(size_t)(ks * 32 + bq * 8 + j) * HID + mt * 16 + tc]);
            w1f[mt][ks] = f;
        }

    // Layer-2 A-fragment: W2 pre-permuted so that hidden unit at C(mt,r) lands at
    // k = (mt>>1)*32 + bq*8 + (mt&1)*4 + r. Rows m>=2 zero.
    s16x8 w2f[4];
    #pragma unroll
    for (int ks = 0; ks < 4; ++ks) {
        s16x8 f;
        #pragma unroll
        for (int j = 0; j < 8; ++j) {
            const int mt = ks * 2 + (j >> 2), r = j & 3;
            f[j] = (tc < 2) ? (short)f2bf(W2[(mt * 16 + bq * 4 + r) * 2 + tc]) : (short)0;
        }
        w2f[ks] = f;
    }

    // b1 packed bf16 (folded into layer-1 acc init): value for C(mt,r) = b1[mt*16+bq*4+r]
    uint2 b1p[8];
    #pragma unroll
    for (int mt = 0; mt < 8; ++mt) {
        const int u0 = mt * 16 + bq * 4;
        b1p[mt].x = (unsigned)f2bf(b1[u0 + 0]) | ((unsigned)f2bf(b1[u0 + 1]) << 16);
        b1p[mt].y = (unsigned)f2bf(b1[u0 + 2]) | ((unsigned)f2bf(b1[u0 + 3]) << 16);
    }
    const float a20 = (bq == 0) ? b2[0] : 0.f;   // layer-2 acc init rows 0,1
    const float a21 = (bq == 0) ? b2[1] : 0.f;

    const int stride = gridDim.x * 4;
    int tile = blockIdx.x * 4 + wid;
    if (tile >= nTiles) return;

    auto GATHER = [&](int s, int d, s16x8 (&xf)[4]) {
        if (BF16H) {
            const s16x8* ps = reinterpret_cast<const s16x8*>(hb + (size_t)s * EMB + bq * 8);
            const s16x8* pd = reinterpret_cast<const s16x8*>(hb + (size_t)d * EMB + bq * 8);
            xf[0] = ps[0]; xf[1] = ps[4];   // src k 0..31 / 32..63  (at bq*8+j)
            xf[2] = pd[0]; xf[3] = pd[4];   // dst k 64..95 / 96..127
        } else {
            const float* ps = h + (size_t)s * EMB + bq * 8;
            const float* pd = h + (size_t)d * EMB + bq * 8;
            xf[0] = load8f(ps); xf[1] = load8f(ps + 32);
            xf[2] = load8f(pd); xf[3] = load8f(pd + 32);
        }
    };
    auto LOADIDX = [&](int tl, int& s, int& d) {
        if (tl < nTiles) {
            const int e = min(tl * 16 + tc, E - 1);
            s = eidx[e]; d = eidx[E + e];
        } else { s = 0; d = 0; }
    };
    auto COMPUTE = [&](int tl, s16x8 (&xf)[4]) {
        f32x4 acc[8];
        #pragma unroll
        for (int mt = 0; mt < 8; ++mt) {   // init = b1 (unpack bf16 -> f32 via shifts)
            acc[mt][0] = __uint_as_float(b1p[mt].x << 16);
            acc[mt][1] = __uint_as_float(b1p[mt].x & 0xffff0000u);
            acc[mt][2] = __uint_as_float(b1p[mt].y << 16);
            acc[mt][3] = __uint_as_float(b1p[mt].y & 0xffff0000u);
        }
        #pragma unroll
        for (int ks = 0; ks < 4; ++ks)
            #pragma unroll
            for (int mt = 0; mt < 8; ++mt)
                acc[mt] = __builtin_amdgcn_mfma_f32_16x16x32_bf16(
                              w1f[mt][ks], xf[ks], acc[mt], 0, 0, 0);

        // ReLU + repack C(mt,r) -> layer-2 B-frag p[ks][j] (pure per-lane relabel)
        s16x8 p[4];
        #pragma unroll
        for (int ks = 0; ks < 4; ++ks)
            #pragma unroll
            for (int j = 0; j < 8; ++j) {
                const int mt = ks * 2 + (j >> 2), r = j & 3;
                p[ks][j] = (short)f2bf(fmaxf(acc[mt][r], 0.f));
            }

        f32x4 o = {a20, a21, 0.f, 0.f};
        #pragma unroll
        for (int ks = 0; ks < 4; ++ks)
            o = __builtin_amdgcn_mfma_f32_16x16x32_bf16(w2f[ks], p[ks], o, 0, 0, 0);

        if (lane < 16) {                   // C2 rows 0,1 live in bq==0 lanes
            const int eo = tl * 16 + lane;
            if (eo < E)
                *reinterpret_cast<float2*>(out + (size_t)eo * 2) =
                    make_float2(o[0], o[1]);
        }
    };

    // ---- depth-2 pipeline: idx 2 tiles ahead, X 1 tile ahead ----
    int sN, dN;
    LOADIDX(tile, sN, dN);
    s16x8 xC[4], xN[4];
    GATHER(sN, dN, xC);
    LOADIDX(tile + stride, sN, dN);

    while (true) {
        GATHER(sN, dN, xN);                    // prefetch next tile's X
        LOADIDX(tile + 2 * stride, sN, dN);    // prefetch idx 2 ahead
        COMPUTE(tile, xC);
        tile += stride;
        if (tile >= nTiles) break;

        GATHER(sN, dN, xC);
        LOADIDX(tile + 2 * stride, sN, dN);
        COMPUTE(tile, xN);
        tile += stride;
        if (tile >= nTiles) break;
    }
}

extern "C" void kernel_launch(void* const* d_in, const int* in_sizes, int n_in,
                              void* d_out, int out_size, void* d_ws, size_t ws_size,
                              hipStream_t stream)
{
    const float* h  = (const float*)d_in[0];
    const int*   ei = (const int*)d_in[1];
    const float* W1 = (const float*)d_in[2];
    const float* b1 = (const float*)d_in[3];
    const float* W2 = (const float*)d_in[4];
    const float* b2 = (const float*)d_in[5];
    float* out = (float*)d_out;

    const int nNodes = in_sizes[0] / EMB;
    const int E      = in_sizes[1] / 2;
    const int nTiles = (E + 15) / 16;
    const size_t hbBytes = (size_t)nNodes * EMB * sizeof(unsigned short);

    const int grid = 512;   // exactly-resident persistent blocks (2/CU at 2 waves/SIMD)

    if (ws_size >= hbBytes) {
        unsigned short* hb = (unsigned short*)d_ws;
        const int n8 = (nNodes * EMB) / 8;
        hipLaunchKernelGGL(conv_h_kernel, dim3((n8 + 255) / 256), dim3(256), 0, stream,
                           h, hb, n8);
        hipLaunchKernelGGL((edge_mlp_mfma2<true>), dim3(grid), dim3(256), 0, stream,
                           h, hb, ei, W1, b1, W2, b2, out, E, nTiles);
    } else {
        hipLaunchKernelGGL((edge_mlp_mfma2<false>), dim3(grid), dim3(256), 0, stream,
                           h, (const unsigned short*)nullptr, ei, W1, b1, W2, b2, out,
                           E, nTiles);
    }
}